// Round 1
// baseline (254.613 us; speedup 1.0000x reference)
//
#include <hip/hip_runtime.h>

#define NUM_NODES 200000
#define DIM 128
#define BATCH 1024
#define K_NEG 5
#define CAP 16
#define BN 128
#define MCHUNK 64
#define LSTRIDE 136   /* padded ushort stride: 272 B rows, 16B-aligned, bank-balanced */
#define THRESH 0.7f
#define FILL (-1.0e9f)

typedef __attribute__((ext_vector_type(8))) short short8;
typedef __attribute__((ext_vector_type(16))) float f32x16;

// round-to-nearest-even float -> bf16 bits (finite inputs only)
__device__ __forceinline__ unsigned short f2bf(float x) {
  unsigned u = __builtin_bit_cast(unsigned, x);
  return (unsigned short)((u + 0x7fffu + ((u >> 16) & 1u)) >> 16);
}

// ---------------- Threefry-2x32 (JAX-compatible) ----------------
__device__ __forceinline__ void tf2x32(unsigned k0, unsigned k1,
                                       unsigned x0, unsigned x1,
                                       unsigned* o0, unsigned* o1) {
  unsigned ks2 = k0 ^ k1 ^ 0x1BD11BDAu;
  unsigned v0 = x0 + k0, v1 = x1 + k1;
#define TFR(r) { v0 += v1; v1 = (v1 << r) | (v1 >> (32 - r)); v1 ^= v0; }
  TFR(13) TFR(15) TFR(26) TFR(6)   v0 += k1;  v1 += ks2 + 1u;
  TFR(17) TFR(29) TFR(16) TFR(24)  v0 += ks2; v1 += k0 + 2u;
  TFR(13) TFR(15) TFR(26) TFR(6)   v0 += k0;  v1 += k1 + 3u;
  TFR(17) TFR(29) TFR(16) TFR(24)  v0 += k1;  v1 += ks2 + 4u;
  TFR(13) TFR(15) TFR(26) TFR(6)   v0 += ks2; v1 += k0 + 5u;
#undef TFR
  *o0 = v0; *o1 = v1;
}

// partitionable-mode random_bits(key, 32, shape) element m (flat index, hi word 0)
__device__ __forceinline__ unsigned rbits32(unsigned ka, unsigned kb, unsigned m) {
  unsigned o0, o1;
  tf2x32(ka, kb, 0u, m, &o0, &o1);
  return o0 ^ o1;
}

// ---------------- kernel 1: normalize src rows -> bf16, zero counters ----------
__global__ void prep_kernel(const float* __restrict__ memory,
                            const int* __restrict__ src_nodes,
                            unsigned short* __restrict__ s16,
                            int* __restrict__ cand_cnt) {
  int tid = threadIdx.x;
  int gid = blockIdx.x * 256 + tid;
  if (gid < BATCH) cand_cnt[gid] = 0;
  int row = blockIdx.x * 4 + (tid >> 6);   // 256 blocks x 4 waves = 1024 rows
  int lane = tid & 63;
  int s = src_nodes[row];
  float2 v = ((const float2*)(memory + (size_t)s * DIM))[lane];
  float ss = v.x * v.x + v.y * v.y;
#pragma unroll
  for (int off = 32; off > 0; off >>= 1) ss += __shfl_xor(ss, off);
  float inv = 1.0f / fmaxf(sqrtf(ss), 1e-12f);
  unsigned p = (unsigned)f2bf(v.x * inv) | ((unsigned)f2bf(v.y * inv) << 16);
  ((unsigned*)s16)[row * 64 + lane] = p;
}

// ---------------- kernel 2: full sim scan with MFMA, collect >0.7 hits --------
__global__ __launch_bounds__(256, 3) void sim_scan_kernel(
    const float* __restrict__ memory,
    const unsigned short* __restrict__ s16,
    const int* __restrict__ dst_nodes,
    int* __restrict__ cand_cnt,
    float* __restrict__ cand_val,
    int* __restrict__ cand_idx) {
  __shared__ unsigned short cT[BN * LSTRIDE];     // 34816 B: normalized node tile
  __shared__ unsigned short aT[MCHUNK * LSTRIDE]; // 17408 B: staged s-chunk
  int tid = threadIdx.x;
  int wid = tid >> 6;
  int lane = tid & 63;
  int half = lane >> 5;   // 0/1
  int l32 = lane & 31;
  int jbase = blockIdx.x * BN;

  // stage + L2-normalize 128 memory rows (each wave: 32 rows, 2 per iter via half-waves)
  for (int r0 = 0; r0 < 16; ++r0) {
    int lr = wid * 32 + r0 * 2 + half;
    int row = jbase + lr;
    float4 v = make_float4(0.f, 0.f, 0.f, 0.f);
    if (row < NUM_NODES) v = ((const float4*)(memory + (size_t)row * DIM))[l32];
    float ss = v.x * v.x + v.y * v.y + v.z * v.z + v.w * v.w;
#pragma unroll
    for (int off = 16; off > 0; off >>= 1) ss += __shfl_xor(ss, off);
    float inv = 1.0f / fmaxf(sqrtf(ss), 1e-12f);
    uint2 p;
    p.x = (unsigned)f2bf(v.x * inv) | ((unsigned)f2bf(v.y * inv) << 16);
    p.y = (unsigned)f2bf(v.z * inv) | ((unsigned)f2bf(v.w * inv) << 16);
    *(uint2*)&cT[lr * LSTRIDE + l32 * 4] = p;
  }
  __syncthreads();

  // preload B fragments: wave wid owns j-subtile [wid*32, wid*32+32)
  short8 bfrag[8];
  int jloc = wid * 32 + l32;
  int khalf = half * 8;
#pragma unroll
  for (int ks = 0; ks < 8; ++ks)
    bfrag[ks] = *(const short8*)&cT[jloc * LSTRIDE + ks * 16 + khalf];
  int gj = jbase + jloc;

  for (int mc = 0; mc < BATCH / MCHUNK; ++mc) {
    __syncthreads();  // protect aT reuse
#pragma unroll
    for (int it = 0; it < 4; ++it) {          // stage 64x128 bf16 = 16 KB
      int r = it * 16 + (tid >> 4);
      int c = (tid & 15) * 8;
      *(uint4*)&aT[r * LSTRIDE + c] = *(const uint4*)&s16[(size_t)(mc * MCHUNK + r) * DIM + c];
    }
    __syncthreads();
#pragma unroll
    for (int ms = 0; ms < MCHUNK / 32; ++ms) {
      short8 afrag[8];
      int mloc = ms * 32 + l32;
#pragma unroll
      for (int ks = 0; ks < 8; ++ks)
        afrag[ks] = *(const short8*)&aT[mloc * LSTRIDE + ks * 16 + khalf];
      f32x16 acc;
#pragma unroll
      for (int i = 0; i < 16; ++i) acc[i] = 0.0f;
#pragma unroll
      for (int ks = 0; ks < 8; ++ks)
        acc = __builtin_amdgcn_mfma_f32_32x32x16_bf16(afrag[ks], bfrag[ks], acc, 0, 0, 0);
      // C/D layout (m74/m101): col = lane&31, row = (reg&3) + 8*(reg>>2) + 4*(lane>>5)
      int ibase = mc * MCHUNK + ms * 32 + 4 * half;
#pragma unroll
      for (int r = 0; r < 16; ++r) {
        float v = acc[r];
        if (v > THRESH) {
          int gi = ibase + (r & 3) + 8 * (r >> 2);
          if (gj < NUM_NODES && gj != dst_nodes[gi]) {
            int p = atomicAdd(&cand_cnt[gi], 1);
            if (p < CAP) {
              cand_val[gi * CAP + p] = v;
              cand_idx[gi * CAP + p] = gj;
            }
          }
        }
      }
    }
  }
}

// ---------------- kernel 3: top-5 per row, threefry negatives, assemble -------
__global__ void finalize_kernel(const int* __restrict__ src_nodes,
                                const int* __restrict__ dst_nodes,
                                const float* __restrict__ labels,
                                const float* __restrict__ ts,
                                const int* __restrict__ cand_cnt,
                                const float* __restrict__ cand_val,
                                const int* __restrict__ cand_idx,
                                float* __restrict__ out) {
  int r = blockIdx.x * 256 + threadIdx.x;
  if (r >= BATCH) return;
  const int TOT = BATCH + BATCH * K_NEG;  // 6144
  int srcv = src_nodes[r];
  float tsv = ts[r];
  out[r] = (float)srcv;
  out[TOT + r] = (float)dst_nodes[r];
  float l = labels[r];
  out[2 * TOT + r] = l * 0.9f + (1.0f - l) * 0.1f;
  out[3 * TOT + r] = tsv;

  int cnt = cand_cnt[r];
  cnt = cnt < CAP ? cnt : CAP;
  float cv[CAP]; int ci[CAP];
  for (int i = 0; i < cnt; ++i) { cv[i] = cand_val[r * CAP + i]; ci[i] = cand_idx[r * CAP + i]; }

  // jax.random.split(key(42)) — partitionable/foldlike: k_i = threefry(key, 0, i)
  unsigned k1a, k1b, k2a, k2b;
  tf2x32(0u, 42u, 0u, 0u, &k1a, &k1b);
  tf2x32(0u, 42u, 0u, 1u, &k2a, &k2b);

  const unsigned span = 200000u;
  const unsigned mult = 167296u;  // (2^16 % span)^2 % span  (== 2^32 % span)

  for (int s = 0; s < K_NEG; ++s) {
    int sel = -1;
    for (int i = 0; i < cnt; ++i)
      if (sel < 0 || cv[i] > cv[sel] || (cv[i] == cv[sel] && ci[i] < ci[sel])) sel = i;
    float v = FILL; int idx = 0;
    if (sel >= 0) { v = cv[sel]; idx = ci[sel]; cv[sel] = FILL; ci[sel] = 0x7fffffff; }
    bool is_real = v > (FILL + 1.0f);

    unsigned m = (unsigned)(r * K_NEG + s);
    unsigned hi = rbits32(k1a, k1b, m);
    unsigned lo = rbits32(k2a, k2b, m);
    unsigned off = ((hi % span) * mult + (lo % span)) % span;  // uint32 wrap, as JAX
    int rd = (int)off;
    if (rd == srcv) rd = (rd + 1) % NUM_NODES;
    int fd = is_real ? idx : rd;

    int mi = (int)m;
    out[BATCH + mi] = (float)srcv;
    out[TOT + BATCH + mi] = (float)fd;
    out[2 * TOT + BATCH + mi] = 0.1f;   // smoothing of label 0
    out[3 * TOT + BATCH + mi] = tsv;
    out[4 * TOT + mi] = v;
  }
}

extern "C" void kernel_launch(void* const* d_in, const int* in_sizes, int n_in,
                              void* d_out, int out_size, void* d_ws, size_t ws_size,
                              hipStream_t stream) {
  const int* src = (const int*)d_in[0];
  const int* dst = (const int*)d_in[1];
  const float* labels = (const float*)d_in[2];
  const float* ts = (const float*)d_in[3];
  const float* memory = (const float*)d_in[4];
  float* out = (float*)d_out;

  char* ws = (char*)d_ws;
  unsigned short* s16 = (unsigned short*)ws;        // 1024*128*2 = 262144 B
  int* cand_cnt = (int*)(ws + 262144);              // 4096 B
  float* cand_val = (float*)(ws + 266240);          // 65536 B
  int* cand_idx = (int*)(ws + 331776);              // 65536 B

  prep_kernel<<<256, 256, 0, stream>>>(memory, src, s16, cand_cnt);
  int jblocks = (NUM_NODES + BN - 1) / BN;          // 1563
  sim_scan_kernel<<<jblocks, 256, 0, stream>>>(memory, s16, dst, cand_cnt, cand_val, cand_idx);
  finalize_kernel<<<(BATCH + 255) / 256, 256, 0, stream>>>(src, dst, labels, ts,
                                                           cand_cnt, cand_val, cand_idx, out);
}

// Round 2
// 209.784 us; speedup vs baseline: 1.2137x; 1.2137x over previous
//
#include <hip/hip_runtime.h>

#define NUM_NODES 200000
#define DIM 128
#define BATCH 1024
#define K_NEG 5
#define CAP 16
#define BN 256            /* j-columns per block (4 waves x 64) */
#define THRESH 0.7f
#define FILL (-1.0e9f)

typedef __attribute__((ext_vector_type(8))) short short8;
typedef __attribute__((ext_vector_type(16))) float f32x16;

// round-to-nearest-even float -> bf16 bits (finite inputs only)
__device__ __forceinline__ unsigned short f2bf(float x) {
  unsigned u = __builtin_bit_cast(unsigned, x);
  return (unsigned short)((u + 0x7fffu + ((u >> 16) & 1u)) >> 16);
}

// ---------------- Threefry-2x32 (JAX-compatible) ----------------
__device__ __forceinline__ void tf2x32(unsigned k0, unsigned k1,
                                       unsigned x0, unsigned x1,
                                       unsigned* o0, unsigned* o1) {
  unsigned ks2 = k0 ^ k1 ^ 0x1BD11BDAu;
  unsigned v0 = x0 + k0, v1 = x1 + k1;
#define TFR(r) { v0 += v1; v1 = (v1 << r) | (v1 >> (32 - r)); v1 ^= v0; }
  TFR(13) TFR(15) TFR(26) TFR(6)   v0 += k1;  v1 += ks2 + 1u;
  TFR(17) TFR(29) TFR(16) TFR(24)  v0 += ks2; v1 += k0 + 2u;
  TFR(13) TFR(15) TFR(26) TFR(6)   v0 += k0;  v1 += k1 + 3u;
  TFR(17) TFR(29) TFR(16) TFR(24)  v0 += k1;  v1 += ks2 + 4u;
  TFR(13) TFR(15) TFR(26) TFR(6)   v0 += ks2; v1 += k0 + 5u;
#undef TFR
  *o0 = v0; *o1 = v1;
}

__device__ __forceinline__ unsigned rbits32(unsigned ka, unsigned kb, unsigned m) {
  unsigned o0, o1;
  tf2x32(ka, kb, 0u, m, &o0, &o1);
  return o0 ^ o1;
}

// ---- kernel 1: normalize src rows -> bf16 A-fragments (fragment-major), zero counters
// Fragment layout: chunk index ((ms*8 + ks)*64 + lane64) is 8 bf16 (16 B) holding
// A[row = ms*32 + (lane64&31)][col = ks*16 + (lane64>>5)*8 + t], t=0..7.
__global__ void prep_kernel(const float* __restrict__ memory,
                            const int* __restrict__ src_nodes,
                            unsigned short* __restrict__ s16f,
                            int* __restrict__ cand_cnt) {
  int tid = threadIdx.x;
  int gid = blockIdx.x * 256 + tid;
  if (gid < BATCH) cand_cnt[gid] = 0;
  int row = blockIdx.x * 4 + (tid >> 6);   // 256 blocks x 4 waves = 1024 rows
  int L = tid & 63;                        // lane within the row's wave; cols 2L,2L+1
  int s = src_nodes[row];
  float2 v = ((const float2*)(memory + (size_t)s * DIM))[L];
  float ss = v.x * v.x + v.y * v.y;
#pragma unroll
  for (int off = 32; off > 0; off >>= 1) ss += __shfl_xor(ss, off);
  float inv = 1.0f / fmaxf(sqrtf(ss), 1e-12f);
  unsigned p = (unsigned)f2bf(v.x * inv) | ((unsigned)f2bf(v.y * inv) << 16);
  int ms = row >> 5, l32 = row & 31;
  int c = L >> 2;             // col chunk = col/8
  int ks = c >> 1, half = c & 1;
  ((unsigned*)s16f)[(((ms * 8 + ks) * 64) + half * 32 + l32) * 4 + (L & 3)] = p;
}

// ---- kernel 2: barrier-free MFMA sim scan, collect >0.7 hits ----
// Each wave owns 64 j-columns (2 B-subtiles); B fragments built in registers,
// A fragments streamed from L2 in fragment-major layout with 1-subtile prefetch.
__global__ __launch_bounds__(256, 2) void sim_scan_kernel(
    const float* __restrict__ memory,
    const unsigned short* __restrict__ s16f,
    const int* __restrict__ dst_nodes,
    int* __restrict__ cand_cnt,
    float* __restrict__ cand_val,
    int* __restrict__ cand_idx) {
  int tid = threadIdx.x;
  int wid = tid >> 6;
  int lane = tid & 63;
  int half = lane >> 5;
  int l32 = lane & 31;
  int jb = blockIdx.x * BN + wid * 64;   // wave's 64-column base

  // ---- build B fragments in registers (L2-normalized node rows -> bf16) ----
  short8 bf0[8], bf1[8];
#pragma unroll
  for (int js = 0; js < 2; ++js) {
    int j = jb + js * 32 + l32;
    bool jv = (j < NUM_NODES);
    const float4* rp4 = (const float4*)(memory + (size_t)j * DIM);
    float4 q[16];
#pragma unroll
    for (int ks = 0; ks < 8; ++ks) {
      // lane (l32,half) holds cols ks*16 + half*8 + 0..7 of row j
      q[ks * 2]     = jv ? rp4[ks * 4 + half * 2]     : make_float4(0.f, 0.f, 0.f, 0.f);
      q[ks * 2 + 1] = jv ? rp4[ks * 4 + half * 2 + 1] : make_float4(0.f, 0.f, 0.f, 0.f);
    }
    float ss = 0.0f;
#pragma unroll
    for (int i = 0; i < 16; ++i)
      ss += q[i].x * q[i].x + q[i].y * q[i].y + q[i].z * q[i].z + q[i].w * q[i].w;
    ss += __shfl_xor(ss, 32);            // combine the two half-rows
    float inv = 1.0f / fmaxf(sqrtf(ss), 1e-12f);
#pragma unroll
    for (int ks = 0; ks < 8; ++ks) {
      float4 a = q[ks * 2], b = q[ks * 2 + 1];
      short8 f;
      f[0] = (short)f2bf(a.x * inv); f[1] = (short)f2bf(a.y * inv);
      f[2] = (short)f2bf(a.z * inv); f[3] = (short)f2bf(a.w * inv);
      f[4] = (short)f2bf(b.x * inv); f[5] = (short)f2bf(b.y * inv);
      f[6] = (short)f2bf(b.z * inv); f[7] = (short)f2bf(b.w * inv);
      if (js == 0) bf0[ks] = f; else bf1[ks] = f;
    }
  }

  // ---- main loop over 32 A-subtiles (whole batch), software-pipelined ----
  const short8* __restrict__ af = (const short8*)s16f;
  short8 acur[8], anext[8];
#pragma unroll
  for (int ks = 0; ks < 8; ++ks) acur[ks] = af[ks * 64 + lane];

  for (int ms = 0; ms < 32; ++ms) {
    if (ms < 31) {
#pragma unroll
      for (int ks = 0; ks < 8; ++ks) anext[ks] = af[((ms + 1) * 8 + ks) * 64 + lane];
    }
    f32x16 acc0, acc1;
#pragma unroll
    for (int i = 0; i < 16; ++i) { acc0[i] = 0.0f; acc1[i] = 0.0f; }
#pragma unroll
    for (int ks = 0; ks < 8; ++ks) {
      acc0 = __builtin_amdgcn_mfma_f32_32x32x16_bf16(acur[ks], bf0[ks], acc0, 0, 0, 0);
      acc1 = __builtin_amdgcn_mfma_f32_32x32x16_bf16(acur[ks], bf1[ks], acc1, 0, 0, 0);
    }
    // cheap pre-check: max over all 32 accumulator elements
    float vm = acc0[0];
#pragma unroll
    for (int i = 1; i < 16; ++i) vm = fmaxf(vm, acc0[i]);
#pragma unroll
    for (int i = 0; i < 16; ++i) vm = fmaxf(vm, acc1[i]);
    if (vm > THRESH) {
      // C/D layout (m74/m101): col = lane&31, row = (reg&3) + 8*(reg>>2) + 4*(lane>>5)
#pragma unroll
      for (int js = 0; js < 2; ++js) {
        int gj = jb + js * 32 + l32;
#pragma unroll
        for (int r = 0; r < 16; ++r) {
          float v = (js == 0) ? acc0[r] : acc1[r];
          if (v > THRESH) {
            int gi = ms * 32 + (r & 3) + 8 * (r >> 2) + 4 * half;
            if (gj < NUM_NODES && gj != dst_nodes[gi]) {
              int p = atomicAdd(&cand_cnt[gi], 1);
              if (p < CAP) {
                cand_val[gi * CAP + p] = v;
                cand_idx[gi * CAP + p] = gj;
              }
            }
          }
        }
      }
    }
#pragma unroll
    for (int ks = 0; ks < 8; ++ks) acur[ks] = anext[ks];
  }
}

// ---- kernel 3: top-5 per row, threefry negatives, assemble ----
__global__ void finalize_kernel(const int* __restrict__ src_nodes,
                                const int* __restrict__ dst_nodes,
                                const float* __restrict__ labels,
                                const float* __restrict__ ts,
                                const int* __restrict__ cand_cnt,
                                const float* __restrict__ cand_val,
                                const int* __restrict__ cand_idx,
                                float* __restrict__ out) {
  int r = blockIdx.x * 256 + threadIdx.x;
  if (r >= BATCH) return;
  const int TOT = BATCH + BATCH * K_NEG;  // 6144
  int srcv = src_nodes[r];
  float tsv = ts[r];
  out[r] = (float)srcv;
  out[TOT + r] = (float)dst_nodes[r];
  float l = labels[r];
  out[2 * TOT + r] = l * 0.9f + (1.0f - l) * 0.1f;
  out[3 * TOT + r] = tsv;

  int cnt = cand_cnt[r];
  cnt = cnt < CAP ? cnt : CAP;
  float cv[CAP]; int ci[CAP];
  for (int i = 0; i < cnt; ++i) { cv[i] = cand_val[r * CAP + i]; ci[i] = cand_idx[r * CAP + i]; }

  // jax.random.split(key(42)) — partitionable/foldlike: k_i = threefry(key, 0, i)
  unsigned k1a, k1b, k2a, k2b;
  tf2x32(0u, 42u, 0u, 0u, &k1a, &k1b);
  tf2x32(0u, 42u, 0u, 1u, &k2a, &k2b);

  const unsigned span = 200000u;
  const unsigned mult = 167296u;  // 2^32 % span

  for (int s = 0; s < K_NEG; ++s) {
    int sel = -1;
    for (int i = 0; i < cnt; ++i)
      if (sel < 0 || cv[i] > cv[sel] || (cv[i] == cv[sel] && ci[i] < ci[sel])) sel = i;
    float v = FILL; int idx = 0;
    if (sel >= 0) { v = cv[sel]; idx = ci[sel]; cv[sel] = FILL; ci[sel] = 0x7fffffff; }
    bool is_real = v > (FILL + 1.0f);

    unsigned m = (unsigned)(r * K_NEG + s);
    unsigned hi = rbits32(k1a, k1b, m);
    unsigned lo = rbits32(k2a, k2b, m);
    unsigned off = ((hi % span) * mult + (lo % span)) % span;  // uint32 wrap, as JAX
    int rd = (int)off;
    if (rd == srcv) rd = (rd + 1) % NUM_NODES;
    int fd = is_real ? idx : rd;

    int mi = (int)m;
    out[BATCH + mi] = (float)srcv;
    out[TOT + BATCH + mi] = (float)fd;
    out[2 * TOT + BATCH + mi] = 0.1f;   // smoothing of label 0
    out[3 * TOT + BATCH + mi] = tsv;
    out[4 * TOT + mi] = v;
  }
}

extern "C" void kernel_launch(void* const* d_in, const int* in_sizes, int n_in,
                              void* d_out, int out_size, void* d_ws, size_t ws_size,
                              hipStream_t stream) {
  const int* src = (const int*)d_in[0];
  const int* dst = (const int*)d_in[1];
  const float* labels = (const float*)d_in[2];
  const float* ts = (const float*)d_in[3];
  const float* memory = (const float*)d_in[4];
  float* out = (float*)d_out;

  char* ws = (char*)d_ws;
  unsigned short* s16f = (unsigned short*)ws;       // 1024*128*2 = 262144 B (fragment-major)
  int* cand_cnt = (int*)(ws + 262144);              // 4096 B
  float* cand_val = (float*)(ws + 266240);          // 65536 B
  int* cand_idx = (int*)(ws + 331776);              // 65536 B

  prep_kernel<<<256, 256, 0, stream>>>(memory, src, s16f, cand_cnt);
  int jblocks = (NUM_NODES + BN - 1) / BN;          // 782
  sim_scan_kernel<<<jblocks, 256, 0, stream>>>(memory, s16f, dst, cand_cnt, cand_val, cand_idx);
  finalize_kernel<<<(BATCH + 255) / 256, 256, 0, stream>>>(src, dst, labels, ts,
                                                           cand_cnt, cand_val, cand_idx, out);
}